// Round 5
// baseline (798.571 us; speedup 1.0000x reference)
//
#include <hip/hip_runtime.h>
#include <math.h>

#define NBINS 28
#define L2E 1.44269504088896340736f

#define EXP2F(x) __builtin_amdgcn_exp2f(x)
#define RCPF(x)  __builtin_amdgcn_rcpf(x)
#define SCHED_FENCE() __builtin_amdgcn_sched_barrier(0)

// workspace / LDS float offsets.  W1/W2 are stored QUAD-MAJOR:
//   sW1 float4[q*8+f]  = W1[f][4q..4q+3] * -log2e   (q=0..3, f=0..7)
//   sW2 float4[q*16+k] = W2[k][4q..4q+3] * -log2e   (k=0..15)
// so the kernel can finish one output-quad at a time (accumulator dies
// immediately -> live set ~95 regs for 2 rows, fits the 128-VGPR cap).
#define WS_TBL 0    // 40 floats: ml_table[d-1] = exp(ml_mlp(d) - 0.25 d), d=1..40
#define WS_W1  64   // 128 floats, quad-major, prescaled by -log2(e)
#define WS_B1  192  // 16, prescaled by -log2(e)
#define WS_W2  208  // 256 floats, quad-major, prescaled by -log2(e)
#define WS_B2  464  // 16, prescaled by -log2(e)
#define WS_W3  480  // 16, prescaled by +log2(e)
#define WS_B3  496  // 1, prescaled by +log2(e)
#define WS_TOT 512

__global__ void prep_kernel(const float* __restrict__ mh_W1, const float* __restrict__ mh_b1,
                            const float* __restrict__ mh_W2, const float* __restrict__ mh_b2,
                            const float* __restrict__ mh_W3, const float* __restrict__ mh_b3,
                            const float* __restrict__ ml_W1, const float* __restrict__ ml_b1,
                            const float* __restrict__ ml_W2, const float* __restrict__ ml_b2,
                            const float* __restrict__ ml_W3, const float* __restrict__ ml_b3,
                            float* __restrict__ ws, float* __restrict__ out_bins) {
    const int t = threadIdx.x;  // 64 threads
    // W1 quad-major: k = (q*8+f)*4 + c  <-  W1[f*16 + q*4 + c]
    for (int k = t; k < 128; k += 64) {
        const int q = k >> 5, f = (k >> 2) & 7, c = k & 3;
        ws[WS_W1 + k] = -L2E * mh_W1[f * 16 + q * 4 + c];
    }
    for (int k = t; k < 16;  k += 64) ws[WS_B1 + k] = -L2E * mh_b1[k];
    // W2 quad-major: k = (q*16+kk)*4 + c  <-  W2[kk*16 + q*4 + c]
    for (int k = t; k < 256; k += 64) {
        const int q = k >> 6, kk = (k >> 2) & 15, c = k & 3;
        ws[WS_W2 + k] = -L2E * mh_W2[kk * 16 + q * 4 + c];
    }
    for (int k = t; k < 16;  k += 64) ws[WS_B2 + k] = -L2E * mh_b2[k];
    for (int k = t; k < 16;  k += 64) ws[WS_W3 + k] =  L2E * mh_W3[k];
    if (t == 0) ws[WS_B3] = L2E * mh_b3[0];

    if (t < 40) {
        const float x = (float)(t + 1);
        float h1[16], h2[16];
        #pragma unroll
        for (int j = 0; j < 16; ++j)
            h1[j] = 1.0f / (1.0f + expf(-(x * ml_W1[j] + ml_b1[j])));
        #pragma unroll
        for (int j = 0; j < 16; ++j) {
            float a = ml_b2[j];
            #pragma unroll
            for (int k = 0; k < 16; ++k) a = fmaf(h1[k], ml_W2[k * 16 + j], a);
            h2[j] = 1.0f / (1.0f + expf(-a));
        }
        float phi = ml_b3[0];
        #pragma unroll
        for (int k = 0; k < 16; ++k) phi = fmaf(h2[k], ml_W3[k], phi);
        const float sc = expf(phi - 0.25f * x);
        ws[WS_TBL + t] = sc;
        if (t < NBINS) out_bins[t] = sc;  // dl2_scores term of output 1
    }
}

// 2 rows/thread (rows 2p, 2p+1), one-shot (no grid-stride -> no LICM
// clustering), quad-major accumulation (accumulators die immediately),
// sched fences every 4 weight loads (transient <= 16 regs).
// launch_bounds(256,2): on this toolchain caps VGPR at 128 (R2: (256,4)->64,
// R3: (256,2)->128; R4 uncapped -> 224 padded alloc, 2 waves/SIMD).
// Live-set estimate ~95 regs -> fits 128 with no spills, 4 waves/SIMD.
__global__ __launch_bounds__(256, 2) void main_kernel(
        const float4* __restrict__ x4,
        const int2* __restrict__ dl2p,
        const int2* __restrict__ ml2p,
        const float* __restrict__ ws,
        float2* __restrict__ out2,
        float* __restrict__ out_bins,
        int npair) {
    __shared__ float s[WS_TOT];
    __shared__ float s_bins[4 * NBINS];
    const int tid = threadIdx.x;
    #pragma unroll
    for (int k = tid; k < WS_TOT; k += 256) s[k] = ws[k];
    if (tid < 4 * NBINS) s_bins[tid] = 0.0f;
    __syncthreads();

    const float4* sW1 = (const float4*)&s[WS_W1];  // [q*8+f]
    const float4* sB1 = (const float4*)&s[WS_B1];
    const float4* sW2 = (const float4*)&s[WS_W2];  // [q*16+k]
    const float4* sB2 = (const float4*)&s[WS_B2];
    const float4* sW3 = (const float4*)&s[WS_W3];

    const int p = blockIdx.x * 256 + tid;
    const bool active = (p < npair);
    const int pc = active ? p : 0;   // clamp loads; discard via `active` at store

    const float4 a0 = x4[4 * pc + 0];
    const float4 a1 = x4[4 * pc + 1];
    const float4 b0 = x4[4 * pc + 2];
    const float4 b1 = x4[4 * pc + 3];
    const int2 dl = dl2p[pc];
    const int2 ml = ml2p[pc];
    const float xf0[8] = {a0.x, a0.y, a0.z, a0.w, a1.x, a1.y, a1.z, a1.w};
    const float xf1[8] = {b0.x, b0.y, b0.z, b0.w, b1.x, b1.y, b1.z, b1.w};

    // ---- layer 1: 8 -> 16, quad-major (weights prescaled by -log2e) ----
    float h10[16], h11[16];
    SCHED_FENCE();
    #pragma unroll
    for (int q = 0; q < 4; ++q) {
        const float4 bq = sB1[q];
        float4 u0 = bq, u1 = bq;
        #pragma unroll
        for (int fc = 0; fc < 8; fc += 4) {
            #pragma unroll
            for (int f = fc; f < fc + 4; ++f) {
                const float4 w = sW1[q * 8 + f];
                u0.x = fmaf(xf0[f], w.x, u0.x); u0.y = fmaf(xf0[f], w.y, u0.y);
                u0.z = fmaf(xf0[f], w.z, u0.z); u0.w = fmaf(xf0[f], w.w, u0.w);
                u1.x = fmaf(xf1[f], w.x, u1.x); u1.y = fmaf(xf1[f], w.y, u1.y);
                u1.z = fmaf(xf1[f], w.z, u1.z); u1.w = fmaf(xf1[f], w.w, u1.w);
            }
            SCHED_FENCE();
        }
        h10[4*q+0] = RCPF(1.0f + EXP2F(u0.x)); h10[4*q+1] = RCPF(1.0f + EXP2F(u0.y));
        h10[4*q+2] = RCPF(1.0f + EXP2F(u0.z)); h10[4*q+3] = RCPF(1.0f + EXP2F(u0.w));
        h11[4*q+0] = RCPF(1.0f + EXP2F(u1.x)); h11[4*q+1] = RCPF(1.0f + EXP2F(u1.y));
        h11[4*q+2] = RCPF(1.0f + EXP2F(u1.z)); h11[4*q+3] = RCPF(1.0f + EXP2F(u1.w));
    }

    // ---- layer 2 + layer 3 fused, quad-major ----
    float phi0 = s[WS_B3], phi1 = phi0;   // prescaled by +log2e
    #pragma unroll
    for (int q = 0; q < 4; ++q) {
        const float4 bq = sB2[q];
        float4 v0 = bq, v1 = bq;
        #pragma unroll
        for (int kc = 0; kc < 16; kc += 4) {
            #pragma unroll
            for (int k = kc; k < kc + 4; ++k) {
                const float4 w = sW2[q * 16 + k];
                v0.x = fmaf(h10[k], w.x, v0.x); v0.y = fmaf(h10[k], w.y, v0.y);
                v0.z = fmaf(h10[k], w.z, v0.z); v0.w = fmaf(h10[k], w.w, v0.w);
                v1.x = fmaf(h11[k], w.x, v1.x); v1.y = fmaf(h11[k], w.y, v1.y);
                v1.z = fmaf(h11[k], w.z, v1.z); v1.w = fmaf(h11[k], w.w, v1.w);
            }
            SCHED_FENCE();
        }
        const float4 w3 = sW3[q];   // prescaled by +log2e
        phi0 = fmaf(RCPF(1.0f + EXP2F(v0.x)), w3.x, phi0);
        phi0 = fmaf(RCPF(1.0f + EXP2F(v0.y)), w3.y, phi0);
        phi0 = fmaf(RCPF(1.0f + EXP2F(v0.z)), w3.z, phi0);
        phi0 = fmaf(RCPF(1.0f + EXP2F(v0.w)), w3.w, phi0);
        phi1 = fmaf(RCPF(1.0f + EXP2F(v1.x)), w3.x, phi1);
        phi1 = fmaf(RCPF(1.0f + EXP2F(v1.y)), w3.y, phi1);
        phi1 = fmaf(RCPF(1.0f + EXP2F(v1.z)), w3.z, phi1);
        phi1 = fmaf(RCPF(1.0f + EXP2F(v1.w)), w3.w, phi1);
    }
    const float sc0 = EXP2F(fmaf((float)dl.x, -0.25f * L2E, phi0));
    const float sc1 = EXP2F(fmaf((float)dl.y, -0.25f * L2E, phi1));

    // ---- epilogue ----
    if (active) {
        const int i0 = min(max(dl.x, 1), 40) - 1;
        const int i1 = min(max(dl.y, 1), 40) - 1;
        const float add0 = (dl.x == ml.x) ? s[WS_TBL + i0] : 0.0f;
        const float add1 = (dl.y == ml.y) ? s[WS_TBL + i1] : 0.0f;
        out2[p] = make_float2(sc0 + add0, sc1 + add1);
        float* myb = &s_bins[(tid >> 6) * NBINS];
        if (dl.x >= 1 && dl.x <= NBINS) unsafeAtomicAdd(&myb[dl.x - 1], sc0);
        if (dl.y >= 1 && dl.y <= NBINS) unsafeAtomicAdd(&myb[dl.y - 1], sc1);
    }

    __syncthreads();
    if (tid < NBINS) {
        const float bsum = s_bins[tid] + s_bins[NBINS + tid] +
                           s_bins[2 * NBINS + tid] + s_bins[3 * NBINS + tid];
        unsafeAtomicAdd(&out_bins[tid], bsum);
    }
}

extern "C" void kernel_launch(void* const* d_in, const int* in_sizes, int n_in,
                              void* d_out, int out_size, void* d_ws, size_t ws_size,
                              hipStream_t stream) {
    const int n = in_sizes[0] / 8;  // N rows (even)

    const float* x_feat = (const float*)d_in[0];
    const float* mh_W1  = (const float*)d_in[1];
    const float* mh_b1  = (const float*)d_in[2];
    const float* mh_W2  = (const float*)d_in[3];
    const float* mh_b2  = (const float*)d_in[4];
    const float* mh_W3  = (const float*)d_in[5];
    const float* mh_b3  = (const float*)d_in[6];
    const float* ml_W1  = (const float*)d_in[7];
    const float* ml_b1  = (const float*)d_in[8];
    const float* ml_W2  = (const float*)d_in[9];
    const float* ml_b2  = (const float*)d_in[10];
    const float* ml_W3  = (const float*)d_in[11];
    const float* ml_b3  = (const float*)d_in[12];
    const int* del_lens = (const int*)d_in[13];
    const int* mh_len   = (const int*)d_in[14];

    float* out      = (float*)d_out;
    float* out_bins = out + n;  // last 28 elements of d_out
    float* ws       = (float*)d_ws;

    prep_kernel<<<dim3(1), dim3(64), 0, stream>>>(
        mh_W1, mh_b1, mh_W2, mh_b2, mh_W3, mh_b3,
        ml_W1, ml_b1, ml_W2, ml_b2, ml_W3, ml_b3,
        ws, out_bins);

    const int npair = n / 2;
    const int nblocks = (npair + 255) / 256;
    main_kernel<<<dim3(nblocks), dim3(256), 0, stream>>>(
        (const float4*)x_feat, (const int2*)del_lens, (const int2*)mh_len,
        ws, (float2*)out, out_bins, npair);
}

// Round 6
// 345.280 us; speedup vs baseline: 2.3128x; 2.3128x over previous
//
#include <hip/hip_runtime.h>
#include <math.h>

#define NBINS 28
#define L2E 1.44269504088896340736f

#define EXP2F(x) __builtin_amdgcn_exp2f(x)
#define RCPF(x)  __builtin_amdgcn_rcpf(x)
#define SCHED_FENCE() __builtin_amdgcn_sched_barrier(0)

// workspace / LDS float offsets.  W1/W2 are stored QUAD-MAJOR:
//   sW1 float4[q*8+f]  = W1[f][4q..4q+3] * -log2e   (q=0..3, f=0..7)
//   sW2 float4[q*16+k] = W2[k][4q..4q+3] * -log2e   (k=0..15)
#define WS_TBL 0    // 40 floats: ml_table[d-1] = exp(ml_mlp(d) - 0.25 d), d=1..40
#define WS_W1  64   // 128 floats, quad-major, prescaled by -log2(e)
#define WS_B1  192  // 16, prescaled by -log2(e)
#define WS_W2  208  // 256 floats, quad-major, prescaled by -log2(e)
#define WS_B2  464  // 16, prescaled by -log2(e)
#define WS_W3  480  // 16, prescaled by +log2(e)
#define WS_B3  496  // 1, prescaled by +log2(e)
#define WS_TOT 512

__global__ void prep_kernel(const float* __restrict__ mh_W1, const float* __restrict__ mh_b1,
                            const float* __restrict__ mh_W2, const float* __restrict__ mh_b2,
                            const float* __restrict__ mh_W3, const float* __restrict__ mh_b3,
                            const float* __restrict__ ml_W1, const float* __restrict__ ml_b1,
                            const float* __restrict__ ml_W2, const float* __restrict__ ml_b2,
                            const float* __restrict__ ml_W3, const float* __restrict__ ml_b3,
                            float* __restrict__ ws, float* __restrict__ out_bins) {
    const int t = threadIdx.x;  // 64 threads
    // W1 quad-major: k = (q*8+f)*4 + c  <-  W1[f*16 + q*4 + c]
    for (int k = t; k < 128; k += 64) {
        const int q = k >> 5, f = (k >> 2) & 7, c = k & 3;
        ws[WS_W1 + k] = -L2E * mh_W1[f * 16 + q * 4 + c];
    }
    for (int k = t; k < 16;  k += 64) ws[WS_B1 + k] = -L2E * mh_b1[k];
    // W2 quad-major: k = (q*16+kk)*4 + c  <-  W2[kk*16 + q*4 + c]
    for (int k = t; k < 256; k += 64) {
        const int q = k >> 6, kk = (k >> 2) & 15, c = k & 3;
        ws[WS_W2 + k] = -L2E * mh_W2[kk * 16 + q * 4 + c];
    }
    for (int k = t; k < 16;  k += 64) ws[WS_B2 + k] = -L2E * mh_b2[k];
    for (int k = t; k < 16;  k += 64) ws[WS_W3 + k] =  L2E * mh_W3[k];
    if (t == 0) ws[WS_B3] = L2E * mh_b3[0];

    if (t < 40) {
        const float x = (float)(t + 1);
        float h1[16], h2[16];
        #pragma unroll
        for (int j = 0; j < 16; ++j)
            h1[j] = 1.0f / (1.0f + expf(-(x * ml_W1[j] + ml_b1[j])));
        #pragma unroll
        for (int j = 0; j < 16; ++j) {
            float a = ml_b2[j];
            #pragma unroll
            for (int k = 0; k < 16; ++k) a = fmaf(h1[k], ml_W2[k * 16 + j], a);
            h2[j] = 1.0f / (1.0f + expf(-a));
        }
        float phi = ml_b3[0];
        #pragma unroll
        for (int k = 0; k < 16; ++k) phi = fmaf(h2[k], ml_W3[k], phi);
        const float sc = expf(phi - 0.25f * x);
        ws[WS_TBL + t] = sc;
        if (t < NBINS) out_bins[t] = sc;  // dl2_scores term of output 1
    }
}

// 2 rows/thread, one-shot, quad-major, fences every 4 weight loads.
// NO launch-bounds VGPR cap: empirical rule from R2/R3/R5 vs R4 — every
// capped build spilled GBs of scratch (the pre-RA scheduler's demand runs
// ~100 regs above the true live set, and when capped the allocator spills
// the difference instead of re-scheduling); the only clean build (R4,
// 236 us) was uncapped. Rationale for 2 rows: the DS pipe is the floor
// (~110 broadcast ds_read_b128 per wave-iter ~= 134 us/device at 1 row);
// amortizing each weight read over 2 rows halves that to ~67 us.
__global__ __launch_bounds__(256) void main_kernel(
        const float4* __restrict__ x4,
        const int2* __restrict__ dl2p,
        const int2* __restrict__ ml2p,
        const float* __restrict__ ws,
        float2* __restrict__ out2,
        float* __restrict__ out_bins,
        int npair) {
    __shared__ float s[WS_TOT];
    __shared__ float s_bins[4 * NBINS];
    const int tid = threadIdx.x;
    #pragma unroll
    for (int k = tid; k < WS_TOT; k += 256) s[k] = ws[k];
    if (tid < 4 * NBINS) s_bins[tid] = 0.0f;
    __syncthreads();

    const float4* sW1 = (const float4*)&s[WS_W1];  // [q*8+f]
    const float4* sB1 = (const float4*)&s[WS_B1];
    const float4* sW2 = (const float4*)&s[WS_W2];  // [q*16+k]
    const float4* sB2 = (const float4*)&s[WS_B2];
    const float4* sW3 = (const float4*)&s[WS_W3];

    const int p = blockIdx.x * 256 + tid;
    const bool active = (p < npair);
    const int pc = active ? p : 0;   // clamp loads; discard via `active` at store

    const float4 a0 = x4[4 * pc + 0];
    const float4 a1 = x4[4 * pc + 1];
    const float4 b0 = x4[4 * pc + 2];
    const float4 b1 = x4[4 * pc + 3];
    const int2 dl = dl2p[pc];
    const int2 ml = ml2p[pc];
    const float xf0[8] = {a0.x, a0.y, a0.z, a0.w, a1.x, a1.y, a1.z, a1.w};
    const float xf1[8] = {b0.x, b0.y, b0.z, b0.w, b1.x, b1.y, b1.z, b1.w};

    // ---- layer 1: 8 -> 16, quad-major (weights prescaled by -log2e) ----
    float h10[16], h11[16];
    SCHED_FENCE();
    #pragma unroll
    for (int q = 0; q < 4; ++q) {
        const float4 bq = sB1[q];
        float4 u0 = bq, u1 = bq;
        #pragma unroll
        for (int fc = 0; fc < 8; fc += 4) {
            #pragma unroll
            for (int f = fc; f < fc + 4; ++f) {
                const float4 w = sW1[q * 8 + f];
                u0.x = fmaf(xf0[f], w.x, u0.x); u0.y = fmaf(xf0[f], w.y, u0.y);
                u0.z = fmaf(xf0[f], w.z, u0.z); u0.w = fmaf(xf0[f], w.w, u0.w);
                u1.x = fmaf(xf1[f], w.x, u1.x); u1.y = fmaf(xf1[f], w.y, u1.y);
                u1.z = fmaf(xf1[f], w.z, u1.z); u1.w = fmaf(xf1[f], w.w, u1.w);
            }
            SCHED_FENCE();
        }
        h10[4*q+0] = RCPF(1.0f + EXP2F(u0.x)); h10[4*q+1] = RCPF(1.0f + EXP2F(u0.y));
        h10[4*q+2] = RCPF(1.0f + EXP2F(u0.z)); h10[4*q+3] = RCPF(1.0f + EXP2F(u0.w));
        h11[4*q+0] = RCPF(1.0f + EXP2F(u1.x)); h11[4*q+1] = RCPF(1.0f + EXP2F(u1.y));
        h11[4*q+2] = RCPF(1.0f + EXP2F(u1.z)); h11[4*q+3] = RCPF(1.0f + EXP2F(u1.w));
    }

    // ---- layer 2 + layer 3 fused, quad-major ----
    float phi0 = s[WS_B3], phi1 = phi0;   // prescaled by +log2e
    #pragma unroll
    for (int q = 0; q < 4; ++q) {
        const float4 bq = sB2[q];
        float4 v0 = bq, v1 = bq;
        #pragma unroll
        for (int kc = 0; kc < 16; kc += 4) {
            #pragma unroll
            for (int k = kc; k < kc + 4; ++k) {
                const float4 w = sW2[q * 16 + k];
                v0.x = fmaf(h10[k], w.x, v0.x); v0.y = fmaf(h10[k], w.y, v0.y);
                v0.z = fmaf(h10[k], w.z, v0.z); v0.w = fmaf(h10[k], w.w, v0.w);
                v1.x = fmaf(h11[k], w.x, v1.x); v1.y = fmaf(h11[k], w.y, v1.y);
                v1.z = fmaf(h11[k], w.z, v1.z); v1.w = fmaf(h11[k], w.w, v1.w);
            }
            SCHED_FENCE();
        }
        const float4 w3 = sW3[q];   // prescaled by +log2e
        phi0 = fmaf(RCPF(1.0f + EXP2F(v0.x)), w3.x, phi0);
        phi0 = fmaf(RCPF(1.0f + EXP2F(v0.y)), w3.y, phi0);
        phi0 = fmaf(RCPF(1.0f + EXP2F(v0.z)), w3.z, phi0);
        phi0 = fmaf(RCPF(1.0f + EXP2F(v0.w)), w3.w, phi0);
        phi1 = fmaf(RCPF(1.0f + EXP2F(v1.x)), w3.x, phi1);
        phi1 = fmaf(RCPF(1.0f + EXP2F(v1.y)), w3.y, phi1);
        phi1 = fmaf(RCPF(1.0f + EXP2F(v1.z)), w3.z, phi1);
        phi1 = fmaf(RCPF(1.0f + EXP2F(v1.w)), w3.w, phi1);
    }
    const float sc0 = EXP2F(fmaf((float)dl.x, -0.25f * L2E, phi0));
    const float sc1 = EXP2F(fmaf((float)dl.y, -0.25f * L2E, phi1));

    // ---- epilogue ----
    if (active) {
        const int i0 = min(max(dl.x, 1), 40) - 1;
        const int i1 = min(max(dl.y, 1), 40) - 1;
        const float add0 = (dl.x == ml.x) ? s[WS_TBL + i0] : 0.0f;
        const float add1 = (dl.y == ml.y) ? s[WS_TBL + i1] : 0.0f;
        out2[p] = make_float2(sc0 + add0, sc1 + add1);
        float* myb = &s_bins[(tid >> 6) * NBINS];
        if (dl.x >= 1 && dl.x <= NBINS) unsafeAtomicAdd(&myb[dl.x - 1], sc0);
        if (dl.y >= 1 && dl.y <= NBINS) unsafeAtomicAdd(&myb[dl.y - 1], sc1);
    }

    __syncthreads();
    if (tid < NBINS) {
        const float bsum = s_bins[tid] + s_bins[NBINS + tid] +
                           s_bins[2 * NBINS + tid] + s_bins[3 * NBINS + tid];
        unsafeAtomicAdd(&out_bins[tid], bsum);
    }
}

extern "C" void kernel_launch(void* const* d_in, const int* in_sizes, int n_in,
                              void* d_out, int out_size, void* d_ws, size_t ws_size,
                              hipStream_t stream) {
    const int n = in_sizes[0] / 8;  // N rows (even)

    const float* x_feat = (const float*)d_in[0];
    const float* mh_W1  = (const float*)d_in[1];
    const float* mh_b1  = (const float*)d_in[2];
    const float* mh_W2  = (const float*)d_in[3];
    const float* mh_b2  = (const float*)d_in[4];
    const float* mh_W3  = (const float*)d_in[5];
    const float* mh_b3  = (const float*)d_in[6];
    const float* ml_W1  = (const float*)d_in[7];
    const float* ml_b1  = (const float*)d_in[8];
    const float* ml_W2  = (const float*)d_in[9];
    const float* ml_b2  = (const float*)d_in[10];
    const float* ml_W3  = (const float*)d_in[11];
    const float* ml_b3  = (const float*)d_in[12];
    const int* del_lens = (const int*)d_in[13];
    const int* mh_len   = (const int*)d_in[14];

    float* out      = (float*)d_out;
    float* out_bins = out + n;  // last 28 elements of d_out
    float* ws       = (float*)d_ws;

    prep_kernel<<<dim3(1), dim3(64), 0, stream>>>(
        mh_W1, mh_b1, mh_W2, mh_b2, mh_W3, mh_b3,
        ml_W1, ml_b1, ml_W2, ml_b2, ml_W3, ml_b3,
        ws, out_bins);

    const int npair = n / 2;
    const int nblocks = (npair + 255) / 256;
    main_kernel<<<dim3(nblocks), dim3(256), 0, stream>>>(
        (const float4*)x_feat, (const int2*)del_lens, (const int2*)mh_len,
        ws, (float2*)out, out_bins, npair);
}